// Round 1
// baseline (152.525 us; speedup 1.0000x reference)
//
#include <hip/hip_runtime.h>

#define TS 64
#define HD 16
#define RAY_EXT 10.0f

__global__ __launch_bounds__(256) void radiance_kernel(
    const float* __restrict__ rays_o,
    const float* __restrict__ rays_d,
    const float* __restrict__ u,      // (T, N)
    const float* __restrict__ aabb,   // (2,3)
    const float* __restrict__ W1,     // (3,16)
    const float* __restrict__ b1,     // (16)
    const float* __restrict__ Wsigma, // (16,1)
    const float* __restrict__ Wcolor, // (16,3)
    const float* __restrict__ Wdir,   // (3,3)
    float* __restrict__ out,          // (N,5)
    int N)
{
    int ray = blockIdx.x * blockDim.x + threadIdx.x;
    if (ray >= N) return;

    const float eps = 1e-9f;

    float ox = rays_o[ray * 3 + 0];
    float oy = rays_o[ray * 3 + 1];
    float oz = rays_o[ray * 3 + 2];
    float dx = rays_d[ray * 3 + 0];
    float dy = rays_d[ray * 3 + 1];
    float dz = rays_d[ray * 3 + 2];

    float a0x = aabb[0], a0y = aabb[1], a0z = aabb[2];
    float a1x = aabb[3], a1y = aabb[4], a1z = aabb[5];

    // slab test
    float dsx = (fabsf(dx) < eps) ? eps : dx;
    float dsy = (fabsf(dy) < eps) ? eps : dy;
    float dsz = (fabsf(dz) < eps) ? eps : dz;
    float t1x = (a0x - ox) / dsx, t2x = (a1x - ox) / dsx;
    float t1y = (a0y - oy) / dsy, t2y = (a1y - oy) / dsy;
    float t1z = (a0z - oz) / dsz, t2z = (a1z - oz) / dsz;
    float tminx = fminf(t1x, t2x), tmaxx = fmaxf(t1x, t2x);
    float tminy = fminf(t1y, t2y), tmaxy = fmaxf(t1y, t2y);
    float tminz = fminf(t1z, t2z), tmaxz = fmaxf(t1z, t2z);
    float tnear = fmaxf(fmaxf(tminx, fmaxf(tminy, tminz)), 0.0f);
    float tfar  = fminf(tmaxx, fminf(tmaxy, tmaxz));

    float* o5 = out + (size_t)ray * 5;
    if (!(tnear < tfar)) {
        o5[0] = 0.0f; o5[1] = 0.0f; o5[2] = 0.0f; o5[3] = 0.0f; o5[4] = 0.0f;
        return;
    }

    // weights into registers (wave-uniform, fully unrolled constant indices)
    float w1a[HD], w1b[HD], w1c[HD], b1r[HD], wsg[HD], wc0[HD], wc1[HD], wc2[HD];
#pragma unroll
    for (int j = 0; j < HD; ++j) {
        w1a[j] = W1[0 * HD + j];
        w1b[j] = W1[1 * HD + j];
        w1c[j] = W1[2 * HD + j];
        b1r[j] = b1[j];
        wsg[j] = Wsigma[j];
        wc0[j] = Wcolor[j * 3 + 0];
        wc1[j] = Wcolor[j * 3 + 1];
        wc2[j] = Wcolor[j * 3 + 2];
    }

    // direction encoding: dirs @ Wdir (computed once per ray)
    float dn = sqrtf(dx * dx + dy * dy + dz * dz);
    float inv_dn = 1.0f / dn;
    float ux = dx * inv_dn, uy = dy * inv_dn, uz = dz * inv_dn;
    float dd0 = ux * Wdir[0] + uy * Wdir[3] + uz * Wdir[6];
    float dd1 = ux * Wdir[1] + uy * Wdir[4] + uz * Wdir[7];
    float dd2 = ux * Wdir[2] + uy * Wdir[5] + uz * Wdir[8];

    const float invT = 1.0f / (float)TS;
    float rng = tfar - tnear;

    float cm0 = 0.f, cm1 = 0.f, cm2 = 0.f, am = 0.f, dm = 0.f;
    float Tr = 1.0f;
    float u_cur = u[ray];  // u[0*N + ray]

#pragma unroll 1
    for (int t = 0; t < TS; ++t) {
        // prefetch next u early so the load hides under the MLP
        float u_next = (t < TS - 1) ? u[(size_t)(t + 1) * N + ray] : 0.0f;

        float ts = fmaf(rng, ((float)t + u_cur) * invT, tnear);

        float x = fmaf(ts, dx, ox);
        float y = fmaf(ts, dy, oy);
        float z = fmaf(ts, dz, oz);

        float h[HD];
#pragma unroll
        for (int j = 0; j < HD; ++j) {
            float v = fmaf(x, w1a[j], fmaf(y, w1b[j], fmaf(z, w1c[j], b1r[j])));
            h[j] = fmaxf(v, 0.0f);
        }

        float s_in = 0.0f;
        float c0 = dd0, c1 = dd1, c2 = dd2;
#pragma unroll
        for (int j = 0; j < HD; ++j) {
            s_in = fmaf(h[j], wsg[j], s_in);
            c0 = fmaf(h[j], wc0[j], c0);
            c1 = fmaf(h[j], wc1[j], c1);
            c2 = fmaf(h[j], wc2[j], c2);
        }

        // softplus (stable): max(x,0) + log1p(exp(-|x|))
        float sigma = fmaxf(s_in, 0.0f) + __logf(1.0f + __expf(-fabsf(s_in)));

        // sigmoid
        float col0 = __builtin_amdgcn_rcpf(1.0f + __expf(-c0));
        float col1 = __builtin_amdgcn_rcpf(1.0f + __expf(-c1));
        float col2 = __builtin_amdgcn_rcpf(1.0f + __expf(-c2));

        float delta;
        if (t < TS - 1) {
            float tsn = fmaf(rng, ((float)(t + 1) + u_next) * invT, tnear);
            delta = tsn - ts;
        } else {
            delta = tfar * RAY_EXT - ts;
        }

        float sd = sigma * delta * dn;
        float e = __expf(-sd);
        float w = (1.0f - e) * Tr;
        Tr *= e;

        cm0 = fmaf(w, col0, cm0);
        cm1 = fmaf(w, col1, cm1);
        cm2 = fmaf(w, col2, cm2);
        am += w;
        dm = fmaf(w, ts, dm);

        u_cur = u_next;
    }

    o5[0] = cm0;
    o5[1] = cm1;
    o5[2] = cm2;
    o5[3] = am;
    o5[4] = dm;
}

extern "C" void kernel_launch(void* const* d_in, const int* in_sizes, int n_in,
                              void* d_out, int out_size, void* d_ws, size_t ws_size,
                              hipStream_t stream) {
    const float* rays_o = (const float*)d_in[0];
    const float* rays_d = (const float*)d_in[1];
    const float* u      = (const float*)d_in[2];
    const float* aabb   = (const float*)d_in[3];
    const float* W1     = (const float*)d_in[4];
    const float* b1     = (const float*)d_in[5];
    const float* Wsigma = (const float*)d_in[6];
    const float* Wcolor = (const float*)d_in[7];
    const float* Wdir   = (const float*)d_in[8];
    float* out = (float*)d_out;

    int N = in_sizes[0] / 3;
    int blocks = (N + 255) / 256;
    radiance_kernel<<<blocks, 256, 0, stream>>>(rays_o, rays_d, u, aabb,
                                                W1, b1, Wsigma, Wcolor, Wdir,
                                                out, N);
}

// Round 2
// 105.296 us; speedup vs baseline: 1.4485x; 1.4485x over previous
//
#include <hip/hip_runtime.h>

#define TS 64
#define HD 16
#define RAY_EXT 10.0f

typedef float v2f __attribute__((ext_vector_type(2)));

__global__ __launch_bounds__(256) void radiance_kernel(
    const float* __restrict__ rays_o,
    const float* __restrict__ rays_d,
    const float* __restrict__ u,      // (T, N)
    const float* __restrict__ aabb,   // (2,3)
    const float* __restrict__ W1,     // (3,16)
    const float* __restrict__ b1,     // (16)
    const float* __restrict__ Wsigma, // (16,1)
    const float* __restrict__ Wcolor, // (16,3)
    const float* __restrict__ Wdir,   // (3,3)
    float* __restrict__ out,          // (N,5)
    int N)
{
    int tid = blockIdx.x * blockDim.x + threadIdx.x;
    int ray = tid >> 1;
    int seg = tid & 1;          // which half of the T range this thread owns
    if (ray >= N) return;

    const float eps = 1e-9f;

    float ox = rays_o[ray * 3 + 0];
    float oy = rays_o[ray * 3 + 1];
    float oz = rays_o[ray * 3 + 2];
    float dx = rays_d[ray * 3 + 0];
    float dy = rays_d[ray * 3 + 1];
    float dz = rays_d[ray * 3 + 2];

    float a0x = aabb[0], a0y = aabb[1], a0z = aabb[2];
    float a1x = aabb[3], a1y = aabb[4], a1z = aabb[5];

    // slab test (identical on both lanes of a pair -> pairwise-uniform branches)
    float dsx = (fabsf(dx) < eps) ? eps : dx;
    float dsy = (fabsf(dy) < eps) ? eps : dy;
    float dsz = (fabsf(dz) < eps) ? eps : dz;
    float t1x = (a0x - ox) / dsx, t2x = (a1x - ox) / dsx;
    float t1y = (a0y - oy) / dsy, t2y = (a1y - oy) / dsy;
    float t1z = (a0z - oz) / dsz, t2z = (a1z - oz) / dsz;
    float tnear = fmaxf(fmaxf(fminf(t1x, t2x), fmaxf(fminf(t1y, t2y), fminf(t1z, t2z))), 0.0f);
    float tfar  = fminf(fmaxf(t1x, t2x), fminf(fmaxf(t1y, t2y), fmaxf(t1z, t2z)));

    float* o5 = out + (size_t)ray * 5;
    if (!(tnear < tfar)) {
        if (seg == 0) {
            o5[0] = 0.0f; o5[1] = 0.0f; o5[2] = 0.0f; o5[3] = 0.0f; o5[4] = 0.0f;
        }
        return;
    }

    // ---- packed (float2) weight registers; uniform addresses -> s_load ----
    v2f w1x[HD/2], w1y[HD/2], w1z[HD/2], b1v[HD/2], wsg[HD/2], wr[HD/2], wg[HD/2], wb[HD/2];
#pragma unroll
    for (int jj = 0; jj < HD / 2; ++jj) {
        int j0 = 2 * jj, j1 = 2 * jj + 1;
        w1x[jj] = v2f{W1[0 * HD + j0], W1[0 * HD + j1]};
        w1y[jj] = v2f{W1[1 * HD + j0], W1[1 * HD + j1]};
        w1z[jj] = v2f{W1[2 * HD + j0], W1[2 * HD + j1]};
        b1v[jj] = v2f{b1[j0], b1[j1]};
        wsg[jj] = v2f{Wsigma[j0], Wsigma[j1]};
        wr[jj]  = v2f{Wcolor[j0 * 3 + 0], Wcolor[j1 * 3 + 0]};
        wg[jj]  = v2f{Wcolor[j0 * 3 + 1], Wcolor[j1 * 3 + 1]};
        wb[jj]  = v2f{Wcolor[j0 * 3 + 2], Wcolor[j1 * 3 + 2]};
    }

    // direction encoding (once per ray)
    float dn = sqrtf(dx * dx + dy * dy + dz * dz);
    float inv_dn = 1.0f / dn;
    float ux = dx * inv_dn, uy = dy * inv_dn, uz = dz * inv_dn;
    float dd0 = ux * Wdir[0] + uy * Wdir[3] + uz * Wdir[6];
    float dd1 = ux * Wdir[1] + uy * Wdir[4] + uz * Wdir[7];
    float dd2 = ux * Wdir[2] + uy * Wdir[5] + uz * Wdir[8];

    const float invT = 1.0f / (float)TS;
    float rng = tfar - tnear;

    float cm0 = 0.f, cm1 = 0.f, cm2 = 0.f, am = 0.f, dm = 0.f;
    float Tr = 1.0f;

    const int t0 = seg * (TS / 2);
    float u_cur = u[(size_t)t0 * N + ray];
    float tf = (float)t0;
    float ts = fmaf(rng, (tf + u_cur) * invT, tnear);

#pragma unroll 1
    for (int t = 0; t < TS / 2; ++t) {
        int g = t0 + t;
        int gn = (g + 1 < TS) ? (g + 1) : (TS - 1);   // clamped prefetch index
        float u_next = u[(size_t)gn * N + ray];

        // next sample position (also next iteration's ts)
        float tsn = fmaf(rng, (tf + 1.0f + u_next) * invT, tnear);
        float delta = (g == TS - 1) ? (tfar * RAY_EXT - ts) : (tsn - ts);

        float x = fmaf(ts, dx, ox);
        float y = fmaf(ts, dy, oy);
        float z = fmaf(ts, dz, oz);
        v2f xx = v2f{x, x}, yy = v2f{y, y}, zz = v2f{z, z};

        // layer 1 (packed): h = relu(xyz @ W1 + b1)
        v2f h2[HD / 2];
#pragma unroll
        for (int jj = 0; jj < HD / 2; ++jj) {
            v2f v = __builtin_elementwise_fma(xx, w1x[jj],
                    __builtin_elementwise_fma(yy, w1y[jj],
                    __builtin_elementwise_fma(zz, w1z[jj], b1v[jj])));
            h2[jj] = __builtin_elementwise_max(v, v2f{0.0f, 0.0f});
        }

        // layer 2 (packed accumulate)
        v2f as = v2f{0.f, 0.f}, a0 = v2f{0.f, 0.f}, a1 = v2f{0.f, 0.f}, a2 = v2f{0.f, 0.f};
#pragma unroll
        for (int jj = 0; jj < HD / 2; ++jj) {
            as = __builtin_elementwise_fma(h2[jj], wsg[jj], as);
            a0 = __builtin_elementwise_fma(h2[jj], wr[jj], a0);
            a1 = __builtin_elementwise_fma(h2[jj], wg[jj], a1);
            a2 = __builtin_elementwise_fma(h2[jj], wb[jj], a2);
        }
        float s_in = as.x + as.y;
        float c0 = (a0.x + a0.y) + dd0;
        float c1 = (a1.x + a1.y) + dd1;
        float c2 = (a2.x + a2.y) + dd2;

        // softplus (stable)
        float sigma = fmaxf(s_in, 0.0f) + __logf(1.0f + __expf(-fabsf(s_in)));

        // sigmoid x3
        float col0 = __builtin_amdgcn_rcpf(1.0f + __expf(-c0));
        float col1 = __builtin_amdgcn_rcpf(1.0f + __expf(-c1));
        float col2 = __builtin_amdgcn_rcpf(1.0f + __expf(-c2));

        float sd = sigma * delta * dn;
        float e = __expf(-sd);
        float w = (1.0f - e) * Tr;
        Tr *= e;

        cm0 = fmaf(w, col0, cm0);
        cm1 = fmaf(w, col1, cm1);
        cm2 = fmaf(w, col2, cm2);
        am += w;
        dm = fmaf(w, ts, dm);

        ts = tsn;
        tf += 1.0f;
    }

    // ---- combine the two segments (lane pair 2r, 2r+1; both lanes active) ----
    float pcm0 = __shfl_xor(cm0, 1, 64);
    float pcm1 = __shfl_xor(cm1, 1, 64);
    float pcm2 = __shfl_xor(cm2, 1, 64);
    float pam  = __shfl_xor(am, 1, 64);
    float pdm  = __shfl_xor(dm, 1, 64);

    if (seg == 0) {
        cm0 = fmaf(Tr, pcm0, cm0);
        cm1 = fmaf(Tr, pcm1, cm1);
        cm2 = fmaf(Tr, pcm2, cm2);
        am  = fmaf(Tr, pam,  am);
        dm  = fmaf(Tr, pdm,  dm);
        o5[0] = cm0;
        o5[1] = cm1;
        o5[2] = cm2;
        o5[3] = am;
        o5[4] = dm;
    }
}

extern "C" void kernel_launch(void* const* d_in, const int* in_sizes, int n_in,
                              void* d_out, int out_size, void* d_ws, size_t ws_size,
                              hipStream_t stream) {
    const float* rays_o = (const float*)d_in[0];
    const float* rays_d = (const float*)d_in[1];
    const float* u      = (const float*)d_in[2];
    const float* aabb   = (const float*)d_in[3];
    const float* W1     = (const float*)d_in[4];
    const float* b1     = (const float*)d_in[5];
    const float* Wsigma = (const float*)d_in[6];
    const float* Wcolor = (const float*)d_in[7];
    const float* Wdir   = (const float*)d_in[8];
    float* out = (float*)d_out;

    int N = in_sizes[0] / 3;
    long long threads = (long long)N * 2;
    int blocks = (int)((threads + 255) / 256);
    radiance_kernel<<<blocks, 256, 0, stream>>>(rays_o, rays_d, u, aabb,
                                                W1, b1, Wsigma, Wcolor, Wdir,
                                                out, N);
}

// Round 4
// 69.529 us; speedup vs baseline: 2.1937x; 1.5144x over previous
//
#include <hip/hip_runtime.h>

#define TS 64
#define HD 16
#define NSEG 4
#define SEGLEN (TS / NSEG)
#define RAY_EXT 10.0f

typedef float v2f __attribute__((ext_vector_type(2)));

__device__ __forceinline__ float fast_exp2(float x) { return __builtin_amdgcn_exp2f(x); }
__device__ __forceinline__ float fast_log2(float x) { return __builtin_amdgcn_logf(x); }

__global__ __launch_bounds__(256) void radiance_kernel(
    const float* __restrict__ rays_o,
    const float* __restrict__ rays_d,
    const float* __restrict__ u,      // (T, N)
    const float* __restrict__ aabb,   // (2,3)
    const float* __restrict__ W1,     // (3,16)
    const float* __restrict__ b1,     // (16)
    const float* __restrict__ Wsigma, // (16,1)
    const float* __restrict__ Wcolor, // (16,3)
    const float* __restrict__ Wdir,   // (3,3)
    float* __restrict__ out,          // (N,5)
    int N)
{
    const float LOG2E = 1.44269504088896340736f;

    int tid = blockIdx.x * blockDim.x + threadIdx.x;
    int ray = tid >> 2;
    int seg = tid & 3;          // quarter of the T range this thread owns
    if (ray >= N) return;

    const float eps = 1e-9f;

    float ox = rays_o[ray * 3 + 0];
    float oy = rays_o[ray * 3 + 1];
    float oz = rays_o[ray * 3 + 2];
    float dx = rays_d[ray * 3 + 0];
    float dy = rays_d[ray * 3 + 1];
    float dz = rays_d[ray * 3 + 2];

    float a0x = aabb[0], a0y = aabb[1], a0z = aabb[2];
    float a1x = aabb[3], a1y = aabb[4], a1z = aabb[5];

    // slab test (identical across the 4 lanes of a ray -> group-uniform branch)
    float dsx = (fabsf(dx) < eps) ? eps : dx;
    float dsy = (fabsf(dy) < eps) ? eps : dy;
    float dsz = (fabsf(dz) < eps) ? eps : dz;
    float t1x = (a0x - ox) / dsx, t2x = (a1x - ox) / dsx;
    float t1y = (a0y - oy) / dsy, t2y = (a1y - oy) / dsy;
    float t1z = (a0z - oz) / dsz, t2z = (a1z - oz) / dsz;
    float tnear = fmaxf(fmaxf(fminf(t1x, t2x), fmaxf(fminf(t1y, t2y), fminf(t1z, t2z))), 0.0f);
    float tfar  = fminf(fmaxf(t1x, t2x), fminf(fmaxf(t1y, t2y), fmaxf(t1z, t2z)));

    float* o5 = out + (size_t)ray * 5;
    if (!(tnear < tfar)) {
        if (seg == 0) {
            o5[0] = 0.0f; o5[1] = 0.0f; o5[2] = 0.0f; o5[3] = 0.0f; o5[4] = 0.0f;
        }
        return;
    }

    // ---- packed weights (uniform addresses). exp2-domain pre-scaling:
    //      Wsigma *= log2e ; Wcolor,dirs@Wdir *= -log2e  (ln2*log2e = 1 folds the rest)
    v2f w1x[HD/2], w1y[HD/2], w1z[HD/2], b1v[HD/2], wsg[HD/2], wr[HD/2], wg[HD/2], wb[HD/2];
#pragma unroll
    for (int jj = 0; jj < HD / 2; ++jj) {
        int j0 = 2 * jj, j1 = 2 * jj + 1;
        w1x[jj] = v2f{W1[0 * HD + j0], W1[0 * HD + j1]};
        w1y[jj] = v2f{W1[1 * HD + j0], W1[1 * HD + j1]};
        w1z[jj] = v2f{W1[2 * HD + j0], W1[2 * HD + j1]};
        b1v[jj] = v2f{b1[j0], b1[j1]};
        wsg[jj] = v2f{Wsigma[j0] * LOG2E, Wsigma[j1] * LOG2E};
        wr[jj]  = v2f{-LOG2E * Wcolor[j0 * 3 + 0], -LOG2E * Wcolor[j1 * 3 + 0]};
        wg[jj]  = v2f{-LOG2E * Wcolor[j0 * 3 + 1], -LOG2E * Wcolor[j1 * 3 + 1]};
        wb[jj]  = v2f{-LOG2E * Wcolor[j0 * 3 + 2], -LOG2E * Wcolor[j1 * 3 + 2]};
    }

    // direction encoding (pre-scaled by -log2e)
    float dn = sqrtf(dx * dx + dy * dy + dz * dz);
    float inv_dn = 1.0f / dn;
    float ux = dx * inv_dn, uy = dy * inv_dn, uz = dz * inv_dn;
    float dd0 = -LOG2E * (ux * Wdir[0] + uy * Wdir[3] + uz * Wdir[6]);
    float dd1 = -LOG2E * (ux * Wdir[1] + uy * Wdir[4] + uz * Wdir[7]);
    float dd2 = -LOG2E * (ux * Wdir[2] + uy * Wdir[5] + uz * Wdir[8]);

    const float invT = 1.0f / (float)TS;
    float rngT = (tfar - tnear) * invT;
    float tfinal = tfar * RAY_EXT;

    // pre-packed broadcast pairs for the MLP input
    v2f dxx = v2f{dx, dx}, dyy = v2f{dy, dy}, dzz = v2f{dz, dz};
    v2f oxx = v2f{ox, ox}, oyy = v2f{oy, oy}, ozz = v2f{oz, oz};

    float cm0 = 0.f, cm1 = 0.f, cm2 = 0.f, am = 0.f, dm = 0.f;
    float Tr = 1.0f;

    const int t0 = seg * SEGLEN;
    // software pipeline: u_a = u for step g+1 (loaded 1 iter ahead)
    float u_cur = u[t0 * N + ray];
    float u_a   = u[(t0 + 1) * N + ray];
    float tf = (float)t0;
    float ts = fmaf(rngT, tf + u_cur, tnear);

#pragma unroll 2
    for (int t = 0; t < SEGLEN; ++t) {
        int g = t0 + t;
        int gp = g + 2 <= TS - 1 ? g + 2 : TS - 1;    // clamped prefetch index
        float u_b = u[gp * N + ray];                  // used NEXT iteration

        float tf1 = tf + 1.0f;
        float tsn = fmaf(rngT, tf1 + u_a, tnear);     // u_a loaded last iteration
        float tend = (g == TS - 1) ? tfinal : tsn;
        float delta = tend - ts;

        v2f ts2 = v2f{ts, ts};
        v2f xx = __builtin_elementwise_fma(ts2, dxx, oxx);
        v2f yy = __builtin_elementwise_fma(ts2, dyy, oyy);
        v2f zz = __builtin_elementwise_fma(ts2, dzz, ozz);

        // layer 1: h = relu(xyz @ W1 + b1)
        v2f h2[HD / 2];
#pragma unroll
        for (int jj = 0; jj < HD / 2; ++jj) {
            v2f v = __builtin_elementwise_fma(xx, w1x[jj],
                    __builtin_elementwise_fma(yy, w1y[jj],
                    __builtin_elementwise_fma(zz, w1z[jj], b1v[jj])));
            h2[jj] = __builtin_elementwise_max(v, v2f{0.0f, 0.0f});
        }

        // layer 2 accumulate (dd' as initial value -> horizontal add gives c' directly)
        v2f as = v2f{0.f, 0.f};
        v2f a0 = v2f{dd0, 0.f}, a1 = v2f{dd1, 0.f}, a2 = v2f{dd2, 0.f};
#pragma unroll
        for (int jj = 0; jj < HD / 2; ++jj) {
            as = __builtin_elementwise_fma(h2[jj], wsg[jj], as);
            a0 = __builtin_elementwise_fma(h2[jj], wr[jj], a0);
            a1 = __builtin_elementwise_fma(h2[jj], wg[jj], a1);
            a2 = __builtin_elementwise_fma(h2[jj], wb[jj], a2);
        }
        float sp = as.x + as.y;        // = (h@Wsigma) * log2e
        float c0 = a0.x + a0.y;        // = -(h@Wcolor + dirs@Wdir) * log2e
        float c1 = a1.x + a1.y;
        float c2 = a2.x + a2.y;

        // softplus+weight in exp2 domain:
        //   e = 2^(-(max(sp,0)+log2(1+2^(-|sp|))) * delta * dn)
        float F = fmaxf(sp, 0.0f) + fast_log2(1.0f + fast_exp2(-fabsf(sp)));
        float e = fast_exp2(-F * (delta * dn));

        // sigmoid: 1/(1+2^(c'))
        float col0 = __builtin_amdgcn_rcpf(1.0f + fast_exp2(c0));
        float col1 = __builtin_amdgcn_rcpf(1.0f + fast_exp2(c1));
        float col2 = __builtin_amdgcn_rcpf(1.0f + fast_exp2(c2));

        float w = (1.0f - e) * Tr;
        Tr *= e;

        cm0 = fmaf(w, col0, cm0);
        cm1 = fmaf(w, col1, cm1);
        cm2 = fmaf(w, col2, cm2);
        am += w;
        dm = fmaf(w, ts, dm);

        ts = tsn;
        tf = tf1;
        u_a = u_b;
    }

    // ---- combine 4 segments: butterfly over the 4-lane group ----
    // round 1 (xor 1): pairs (0,1),(2,3); round 2 (xor 2): (01,23).
    // even lanes of each pair end with the correctly-ordered combined value.
#pragma unroll
    for (int x = 1; x <= 2; x <<= 1) {
        float pcm0 = __shfl_xor(cm0, x, 64);
        float pcm1 = __shfl_xor(cm1, x, 64);
        float pcm2 = __shfl_xor(cm2, x, 64);
        float pam  = __shfl_xor(am, x, 64);
        float pdm  = __shfl_xor(dm, x, 64);
        float pTr  = __shfl_xor(Tr, x, 64);
        cm0 = fmaf(Tr, pcm0, cm0);
        cm1 = fmaf(Tr, pcm1, cm1);
        cm2 = fmaf(Tr, pcm2, cm2);
        am  = fmaf(Tr, pam,  am);
        dm  = fmaf(Tr, pdm,  dm);
        Tr *= pTr;
    }

    if (seg == 0) {
        o5[0] = cm0;
        o5[1] = cm1;
        o5[2] = cm2;
        o5[3] = am;
        o5[4] = dm;
    }
}

extern "C" void kernel_launch(void* const* d_in, const int* in_sizes, int n_in,
                              void* d_out, int out_size, void* d_ws, size_t ws_size,
                              hipStream_t stream) {
    const float* rays_o = (const float*)d_in[0];
    const float* rays_d = (const float*)d_in[1];
    const float* u      = (const float*)d_in[2];
    const float* aabb   = (const float*)d_in[3];
    const float* W1     = (const float*)d_in[4];
    const float* b1     = (const float*)d_in[5];
    const float* Wsigma = (const float*)d_in[6];
    const float* Wcolor = (const float*)d_in[7];
    const float* Wdir   = (const float*)d_in[8];
    float* out = (float*)d_out;

    int N = in_sizes[0] / 3;
    long long threads = (long long)N * NSEG;
    int blocks = (int)((threads + 255) / 256);
    radiance_kernel<<<blocks, 256, 0, stream>>>(rays_o, rays_d, u, aabb,
                                                W1, b1, Wsigma, Wcolor, Wdir,
                                                out, N);
}

// Round 9
// 64.898 us; speedup vs baseline: 2.3503x; 1.0714x over previous
//
#include <hip/hip_runtime.h>

#define TS 64
#define HD 16
#define SEGLEN 16
#define RAY_EXT 10.0f

typedef float    v4f __attribute__((ext_vector_type(4)));
typedef _Float16 v8h __attribute__((ext_vector_type(8)));
typedef unsigned v4u __attribute__((ext_vector_type(4)));

__device__ __forceinline__ float fast_exp2(float x) { return __builtin_amdgcn_exp2f(x); }
__device__ __forceinline__ float fast_log2(float x) { return __builtin_amdgcn_logf(x); }

// pack two f32 into packed f16x2 (v_cvt_pkrtz_f16_f32)
__device__ __forceinline__ unsigned pack_f16x2(float a, float b) {
#if __has_builtin(__builtin_amdgcn_cvt_pkrtz)
    return __builtin_bit_cast(unsigned, __builtin_amdgcn_cvt_pkrtz(a, b));
#else
    unsigned r;
    asm("v_cvt_pkrtz_f16_f32 %0, %1, %2" : "=v"(r) : "v"(a), "v"(b));
    return r;
#endif
}

// fragment with k-slots 0..3 live, 4..7 zero
__device__ __forceinline__ v8h make_frag(unsigned lo, unsigned hi) {
    return __builtin_bit_cast(v8h, (v4u){lo, hi, 0u, 0u});
}

__device__ __forceinline__ v4f mfma32(v8h a, v8h b, v4f c) {
    return __builtin_amdgcn_mfma_f32_16x16x32_f16(a, b, c, 0, 0, 0);
}

__global__ __launch_bounds__(256) void radiance_kernel(
    const float* __restrict__ rays_o,
    const float* __restrict__ rays_d,
    const float* __restrict__ u,      // (T, N)
    const float* __restrict__ aabb,   // (2,3)
    const float* __restrict__ W1,     // (3,16)
    const float* __restrict__ b1,     // (16)
    const float* __restrict__ Wsigma, // (16,1)
    const float* __restrict__ Wcolor, // (16,3)
    const float* __restrict__ Wdir,   // (3,3)
    float* __restrict__ out,          // (N,5)
    int N)
{
    const float LOG2E = 1.44269504088896340736f;
    const float eps = 1e-9f;

    int tid  = blockIdx.x * blockDim.x + threadIdx.x;
    int lane = threadIdx.x & 63;
    int s    = lane & 15;     // ray-within-wave == MFMA column
    int grp  = lane >> 4;     // segment 0..3     == MFMA k/row block
    int wave = tid >> 6;
    int ray  = wave * 16 + s;

    float ox = rays_o[ray * 3 + 0];
    float oy = rays_o[ray * 3 + 1];
    float oz = rays_o[ray * 3 + 2];
    float dx = rays_d[ray * 3 + 0];
    float dy = rays_d[ray * 3 + 1];
    float dz = rays_d[ray * 3 + 2];

    float a0x = aabb[0], a0y = aabb[1], a0z = aabb[2];
    float a1x = aabb[3], a1y = aabb[4], a1z = aabb[5];

    // slab test (no early return: MFMA needs full waves)
    float dsx = (fabsf(dx) < eps) ? eps : dx;
    float dsy = (fabsf(dy) < eps) ? eps : dy;
    float dsz = (fabsf(dz) < eps) ? eps : dz;
    float t1x = (a0x - ox) / dsx, t2x = (a1x - ox) / dsx;
    float t1y = (a0y - oy) / dsy, t2y = (a1y - oy) / dsy;
    float t1z = (a0z - oz) / dsz, t2z = (a1z - oz) / dsz;
    float tnear = fmaxf(fmaxf(fminf(t1x, t2x), fmaxf(fminf(t1y, t2y), fminf(t1z, t2z))), 0.0f);
    float tfar  = fminf(fmaxf(t1x, t2x), fminf(fmaxf(t1y, t2y), fmaxf(t1z, t2z)));
    bool active = tnear < tfar;
    // sanitize inactive rays: pipeline stays finite, all weights w == 0.
    if (!active) { tnear = 0.0f; tfar = 0.0f; }

    // ---- A1 values (2 u32, lane-resident): A1[m=s][slot i] = {W1[0][s],W1[1][s],W1[2][s],b1[s]}
    unsigned w1lo = pack_f16x2(W1[0 * HD + s], W1[1 * HD + s]);
    unsigned w1hi = pack_f16x2(W1[2 * HD + s], b1[s]);

    // ---- A2 values: row m = s -> output o = s&3, owner pass = s>>2.
    //      A2[m=s][slot i] = W2eff[o][4*grp + i], pre-scaled into exp2 domain.
    int oidx = s & 3;
    int rgrp = s >> 2;
    float w2v0, w2v1, w2v2, w2v3;
    {
        int k0 = 4 * grp;
        if (oidx == 0) {
            w2v0 = LOG2E * Wsigma[k0 + 0]; w2v1 = LOG2E * Wsigma[k0 + 1];
            w2v2 = LOG2E * Wsigma[k0 + 2]; w2v3 = LOG2E * Wsigma[k0 + 3];
        } else {
            int c = oidx - 1;
            w2v0 = -LOG2E * Wcolor[(k0 + 0) * 3 + c];
            w2v1 = -LOG2E * Wcolor[(k0 + 1) * 3 + c];
            w2v2 = -LOG2E * Wcolor[(k0 + 2) * 3 + c];
            w2v3 = -LOG2E * Wcolor[(k0 + 3) * 3 + c];
        }
    }
    unsigned a2lo = pack_f16x2(w2v0, w2v1);
    unsigned a2hi = pack_f16x2(w2v2, w2v3);

    // direction encoding (pre-scaled by -log2e), per-ray
    float dn = sqrtf(dx * dx + dy * dy + dz * dz);
    float inv_dn = 1.0f / dn;
    float ux = dx * inv_dn, uy = dy * inv_dn, uz = dz * inv_dn;
    float dd0 = -LOG2E * (ux * Wdir[0] + uy * Wdir[3] + uz * Wdir[6]);
    float dd1 = -LOG2E * (ux * Wdir[1] + uy * Wdir[4] + uz * Wdir[7]);
    float dd2 = -LOG2E * (ux * Wdir[2] + uy * Wdir[5] + uz * Wdir[8]);

    const float invT = 1.0f / (float)TS;
    float rngT = (tfar - tnear) * invT;
    float tfinal = tfar * RAY_EXT;

    const int t0 = grp * SEGLEN;
    float t0f = (float)t0;

    // rolling u prefetch (2 ahead)
    float u_cur = u[(size_t)t0 * N + ray];
    float u_nxt = u[(size_t)(t0 + 1) * N + ray];

    float cm0 = 0.f, cm1 = 0.f, cm2 = 0.f, am = 0.f, dm = 0.f;
    float Tr = 1.0f;
    float ts = fmaf(rngT, t0f + u_cur, tnear);

#pragma unroll 4
    for (int t = 0; t < SEGLEN; ++t) {
        int gp = t0 + t + 2; gp = gp < TS - 1 ? gp : TS - 1;
        float u_fut = u[(size_t)gp * N + ray];        // used NEXT iteration

        float tf1 = t0f + (float)(t + 1);
        float tsn = fmaf(rngT, tf1 + u_nxt, tnear);
        float tend = (t == SEGLEN - 1) ? ((grp == 3) ? tfinal : tsn) : tsn;
        float delta = tend - ts;

        float x = fmaf(ts, dx, ox);
        float y = fmaf(ts, dy, oy);
        float z = fmaf(ts, dz, oz);
        // B1 (unconditional; per-pass selection lives on the A side)
        v8h bin = make_frag(pack_f16x2(x, y), pack_f16x2(z, 1.0f));

        v4f acc = {0.f, 0.f, 0.f, 0.f};
#pragma unroll
        for (int p = 0; p < 4; ++p) {
            bool own1 = (grp == p);
            v8h a1 = make_frag(own1 ? w1lo : 0u, own1 ? w1hi : 0u);
            // layer 1, pass p: only k-block p of A alive -> D1 = h of (ray s, segment p)
            v4f d1 = mfma32(a1, bin, (v4f){0.f, 0.f, 0.f, 0.f});
            // relu + repack: D1 row (l>>4)*4+r -> B2 slot r at lane group l>>4
            unsigned hlo = pack_f16x2(fmaxf(d1[0], 0.f), fmaxf(d1[1], 0.f));
            unsigned hhi = pack_f16x2(fmaxf(d1[2], 0.f), fmaxf(d1[3], 0.f));
            bool own2 = (rgrp == p);
            v8h a2 = make_frag(own2 ? a2lo : 0u, own2 ? a2hi : 0u);
            // layer 2, pass p: rows 4p..4p+3 of A2 alive -> lands on group-p lanes' regs
            acc = mfma32(a2, make_frag(hlo, hhi), acc);
        }

        // acc[0] = sigma-logit*log2e ; acc[1..3] = -color-logit*log2e (sans dir term)
        float sp = acc[0];
        float c0 = acc[1] + dd0;
        float c1 = acc[2] + dd1;
        float c2 = acc[3] + dd2;

        float F = fmaxf(sp, 0.0f) + fast_log2(1.0f + fast_exp2(-fabsf(sp)));
        float e = fast_exp2(-F * (delta * dn));

        float col0 = __builtin_amdgcn_rcpf(1.0f + fast_exp2(c0));
        float col1 = __builtin_amdgcn_rcpf(1.0f + fast_exp2(c1));
        float col2 = __builtin_amdgcn_rcpf(1.0f + fast_exp2(c2));

        float w = (1.0f - e) * Tr;
        Tr *= e;

        cm0 = fmaf(w, col0, cm0);
        cm1 = fmaf(w, col1, cm1);
        cm2 = fmaf(w, col2, cm2);
        am += w;
        dm = fmaf(w, ts, dm);

        ts = tsn;
        u_nxt = u_fut;
    }

    // ---- combine 4 segments across lane groups: butterfly xor 16, then 32.
    // Earlier-segment lanes compute ordered results; later lanes' junk never read.
#pragma unroll
    for (int x = 16; x <= 32; x <<= 1) {
        float pcm0 = __shfl_xor(cm0, x, 64);
        float pcm1 = __shfl_xor(cm1, x, 64);
        float pcm2 = __shfl_xor(cm2, x, 64);
        float pam  = __shfl_xor(am, x, 64);
        float pdm  = __shfl_xor(dm, x, 64);
        float pTr  = __shfl_xor(Tr, x, 64);
        cm0 = fmaf(Tr, pcm0, cm0);
        cm1 = fmaf(Tr, pcm1, cm1);
        cm2 = fmaf(Tr, pcm2, cm2);
        am  = fmaf(Tr, pam,  am);
        dm  = fmaf(Tr, pdm,  dm);
        Tr *= pTr;
    }

    if (grp == 0) {
        float* o5 = out + (size_t)ray * 5;
        o5[0] = active ? cm0 : 0.0f;
        o5[1] = active ? cm1 : 0.0f;
        o5[2] = active ? cm2 : 0.0f;
        o5[3] = active ? am  : 0.0f;
        o5[4] = active ? dm  : 0.0f;
    }
}

extern "C" void kernel_launch(void* const* d_in, const int* in_sizes, int n_in,
                              void* d_out, int out_size, void* d_ws, size_t ws_size,
                              hipStream_t stream) {
    const float* rays_o = (const float*)d_in[0];
    const float* rays_d = (const float*)d_in[1];
    const float* u      = (const float*)d_in[2];
    const float* aabb   = (const float*)d_in[3];
    const float* W1     = (const float*)d_in[4];
    const float* b1     = (const float*)d_in[5];
    const float* Wsigma = (const float*)d_in[6];
    const float* Wcolor = (const float*)d_in[7];
    const float* Wdir   = (const float*)d_in[8];
    float* out = (float*)d_out;

    int N = in_sizes[0] / 3;
    long long threads = (long long)N * 4;   // 4 lanes (segments) per ray
    int blocks = (int)((threads + 255) / 256);
    radiance_kernel<<<blocks, 256, 0, stream>>>(rays_o, rays_d, u, aabb,
                                                W1, b1, Wsigma, Wcolor, Wdir,
                                                out, N);
}

// Round 10
// 57.832 us; speedup vs baseline: 2.6374x; 1.1222x over previous
//
#include <hip/hip_runtime.h>

#define TS 64
#define HD 16
#define SEGLEN 16
#define RAY_EXT 10.0f

typedef float    v4f __attribute__((ext_vector_type(4)));
typedef _Float16 v8h __attribute__((ext_vector_type(8)));
typedef unsigned v4u __attribute__((ext_vector_type(4)));

__device__ __forceinline__ float fast_exp2(float x) { return __builtin_amdgcn_exp2f(x); }
__device__ __forceinline__ float fast_log2(float x) { return __builtin_amdgcn_logf(x); }

// pack two f32 into packed f16x2 (v_cvt_pkrtz_f16_f32)
__device__ __forceinline__ unsigned pack_f16x2(float a, float b) {
#if __has_builtin(__builtin_amdgcn_cvt_pkrtz)
    return __builtin_bit_cast(unsigned, __builtin_amdgcn_cvt_pkrtz(a, b));
#else
    unsigned r;
    asm("v_cvt_pkrtz_f16_f32 %0, %1, %2" : "=v"(r) : "v"(a), "v"(b));
    return r;
#endif
}

// packed f16 relu: max(x, 0) on both halves
__device__ __forceinline__ unsigned pk_relu(unsigned x, unsigned z) {
    unsigned r;
    asm("v_pk_max_f16 %0, %1, %2" : "=v"(r) : "v"(x), "v"(z));
    return r;
}

// fragment with k-slots 0..3 live, 4..7 zero
__device__ __forceinline__ v8h make_frag(unsigned lo, unsigned hi) {
    return __builtin_bit_cast(v8h, (v4u){lo, hi, 0u, 0u});
}

__device__ __forceinline__ v4f mfma32(v8h a, v8h b, v4f c) {
    return __builtin_amdgcn_mfma_f32_16x16x32_f16(a, b, c, 0, 0, 0);
}

__global__ __launch_bounds__(256) void radiance_kernel(
    const float* __restrict__ rays_o,
    const float* __restrict__ rays_d,
    const float* __restrict__ u,      // (T, N)
    const float* __restrict__ aabb,   // (2,3)
    const float* __restrict__ W1,     // (3,16)
    const float* __restrict__ b1,     // (16)
    const float* __restrict__ Wsigma, // (16,1)
    const float* __restrict__ Wcolor, // (16,3)
    const float* __restrict__ Wdir,   // (3,3)
    float* __restrict__ out,          // (N,5)
    int N)
{
    const float LOG2E = 1.44269504088896340736f;
    const float eps = 1e-9f;

    int tid  = blockIdx.x * blockDim.x + threadIdx.x;
    int lane = threadIdx.x & 63;
    int s    = lane & 15;     // ray-within-wave == MFMA column
    int grp  = lane >> 4;     // segment 0..3     == MFMA k/row block
    int wave = tid >> 6;
    int ray  = wave * 16 + s;

    float ox = rays_o[ray * 3 + 0];
    float oy = rays_o[ray * 3 + 1];
    float oz = rays_o[ray * 3 + 2];
    float dx = rays_d[ray * 3 + 0];
    float dy = rays_d[ray * 3 + 1];
    float dz = rays_d[ray * 3 + 2];

    float a0x = aabb[0], a0y = aabb[1], a0z = aabb[2];
    float a1x = aabb[3], a1y = aabb[4], a1z = aabb[5];

    // slab test (no early return: MFMA needs full waves)
    float dsx = (fabsf(dx) < eps) ? eps : dx;
    float dsy = (fabsf(dy) < eps) ? eps : dy;
    float dsz = (fabsf(dz) < eps) ? eps : dz;
    float t1x = (a0x - ox) / dsx, t2x = (a1x - ox) / dsx;
    float t1y = (a0y - oy) / dsy, t2y = (a1y - oy) / dsy;
    float t1z = (a0z - oz) / dsz, t2z = (a1z - oz) / dsz;
    float tnear = fmaxf(fmaxf(fminf(t1x, t2x), fmaxf(fminf(t1y, t2y), fminf(t1z, t2z))), 0.0f);
    float tfar  = fminf(fmaxf(t1x, t2x), fminf(fmaxf(t1y, t2y), fmaxf(t1z, t2z)));
    bool active = tnear < tfar;
    // sanitize inactive rays: pipeline stays finite, all weights w == 0.
    if (!active) { tnear = 0.0f; tfar = 0.0f; }

    // ---- A1 values: A1[m=s][slot i] = {W1[0][s],W1[1][s],W1[2][s],b1[s]}
    unsigned w1lo = pack_f16x2(W1[0 * HD + s], W1[1 * HD + s]);
    unsigned w1hi = pack_f16x2(W1[2 * HD + s], b1[s]);

    // ---- A2 values: row m = s -> output o = s&3, owner pass = s>>2.
    //      A2[m=s][slot i] = W2eff[o][4*grp + i], pre-scaled into exp2 domain.
    int oidx = s & 3;
    int rgrp = s >> 2;
    float w2v0, w2v1, w2v2, w2v3;
    {
        int k0 = 4 * grp;
        if (oidx == 0) {
            w2v0 = LOG2E * Wsigma[k0 + 0]; w2v1 = LOG2E * Wsigma[k0 + 1];
            w2v2 = LOG2E * Wsigma[k0 + 2]; w2v3 = LOG2E * Wsigma[k0 + 3];
        } else {
            int c = oidx - 1;
            w2v0 = -LOG2E * Wcolor[(k0 + 0) * 3 + c];
            w2v1 = -LOG2E * Wcolor[(k0 + 1) * 3 + c];
            w2v2 = -LOG2E * Wcolor[(k0 + 2) * 3 + c];
            w2v3 = -LOG2E * Wcolor[(k0 + 3) * 3 + c];
        }
    }
    unsigned a2lo = pack_f16x2(w2v0, w2v1);
    unsigned a2hi = pack_f16x2(w2v2, w2v3);

    // ---- hoisted per-pass masked fragments (lane-constant; static indexing only)
    v8h a1f[4], a2f[4];
#pragma unroll
    for (int p = 0; p < 4; ++p) {
        a1f[p] = make_frag((grp == p) ? w1lo : 0u, (grp == p) ? w1hi : 0u);
        a2f[p] = make_frag((rgrp == p) ? a2lo : 0u, (rgrp == p) ? a2hi : 0u);
    }
    const v4f zero4 = {0.f, 0.f, 0.f, 0.f};
    unsigned zpk = 0u;   // packed f16 zero for pk_relu
    asm volatile("" : "+v"(zpk));   // keep in a VGPR, hoisted

    // direction encoding (pre-scaled by -log2e), per-ray
    float dn = sqrtf(dx * dx + dy * dy + dz * dz);
    float inv_dn = 1.0f / dn;
    float ux = dx * inv_dn, uy = dy * inv_dn, uz = dz * inv_dn;
    float dd0 = -LOG2E * (ux * Wdir[0] + uy * Wdir[3] + uz * Wdir[6]);
    float dd1 = -LOG2E * (ux * Wdir[1] + uy * Wdir[4] + uz * Wdir[7]);
    float dd2 = -LOG2E * (ux * Wdir[2] + uy * Wdir[5] + uz * Wdir[8]);

    const float invT = 1.0f / (float)TS;
    float rngT = (tfar - tnear) * invT;
    float tfinal = tfar * RAY_EXT;

    const int t0 = grp * SEGLEN;
    float t0f = (float)t0;

    // rolling u prefetch (2 ahead)
    float u_cur = u[(size_t)t0 * N + ray];
    float u_nxt = u[(size_t)(t0 + 1) * N + ray];

    float cm0 = 0.f, cm1 = 0.f, cm2 = 0.f, am = 0.f, dm = 0.f;
    float Tr = 1.0f;
    float ts = fmaf(rngT, t0f + u_cur, tnear);

#pragma unroll
    for (int t = 0; t < SEGLEN; ++t) {
        int gp = t0 + t + 2; gp = gp < TS - 1 ? gp : TS - 1;
        float u_fut = u[(size_t)gp * N + ray];        // used NEXT iteration

        float tf1 = t0f + (float)(t + 1);
        float tsn = fmaf(rngT, tf1 + u_nxt, tnear);
        // t == SEGLEN-1 is compile-time under full unroll; grp==3 select is per-lane
        float delta;
        if (t == SEGLEN - 1)
            delta = ((grp == 3) ? tfinal : tsn) - ts;
        else
            delta = tsn - ts;

        float x = fmaf(ts, dx, ox);
        float y = fmaf(ts, dy, oy);
        float z = fmaf(ts, dz, oz);
        v8h bin = make_frag(pack_f16x2(x, y), pack_f16x2(z, 1.0f));

        // ---- layer 1: 4 independent MFMAs (only mutual dep: bin)
        v4f d1_0 = mfma32(a1f[0], bin, zero4);
        v4f d1_1 = mfma32(a1f[1], bin, zero4);
        v4f d1_2 = mfma32(a1f[2], bin, zero4);
        v4f d1_3 = mfma32(a1f[3], bin, zero4);

        // ---- relu in packed f16 (pack then pk_max vs 0)
        v8h h0 = make_frag(pk_relu(pack_f16x2(d1_0[0], d1_0[1]), zpk),
                           pk_relu(pack_f16x2(d1_0[2], d1_0[3]), zpk));
        v8h h1 = make_frag(pk_relu(pack_f16x2(d1_1[0], d1_1[1]), zpk),
                           pk_relu(pack_f16x2(d1_1[2], d1_1[3]), zpk));
        v8h h2 = make_frag(pk_relu(pack_f16x2(d1_2[0], d1_2[1]), zpk),
                           pk_relu(pack_f16x2(d1_2[2], d1_2[3]), zpk));
        v8h h3 = make_frag(pk_relu(pack_f16x2(d1_3[0], d1_3[1]), zpk),
                           pk_relu(pack_f16x2(d1_3[2], d1_3[3]), zpk));

        // ---- layer 2: two independent 2-deep chains, then combine
        v4f accA = mfma32(a2f[1], h1, mfma32(a2f[0], h0, zero4));
        v4f accB = mfma32(a2f[3], h3, mfma32(a2f[2], h2, zero4));
        v4f acc = accA + accB;

        // acc[0] = sigma-logit*log2e ; acc[1..3] = -color-logit*log2e (sans dir term)
        float sp = acc[0];
        float c0 = acc[1] + dd0;
        float c1 = acc[2] + dd1;
        float c2 = acc[3] + dd2;

        float F = fmaxf(sp, 0.0f) + fast_log2(1.0f + fast_exp2(-fabsf(sp)));
        float e = fast_exp2(-F * (delta * dn));

        float col0 = __builtin_amdgcn_rcpf(1.0f + fast_exp2(c0));
        float col1 = __builtin_amdgcn_rcpf(1.0f + fast_exp2(c1));
        float col2 = __builtin_amdgcn_rcpf(1.0f + fast_exp2(c2));

        float w = (1.0f - e) * Tr;
        Tr *= e;

        cm0 = fmaf(w, col0, cm0);
        cm1 = fmaf(w, col1, cm1);
        cm2 = fmaf(w, col2, cm2);
        am += w;
        dm = fmaf(w, ts, dm);

        ts = tsn;
        u_nxt = u_fut;
    }

    // ---- combine 4 segments across lane groups: butterfly xor 16, then 32.
#pragma unroll
    for (int x = 16; x <= 32; x <<= 1) {
        float pcm0 = __shfl_xor(cm0, x, 64);
        float pcm1 = __shfl_xor(cm1, x, 64);
        float pcm2 = __shfl_xor(cm2, x, 64);
        float pam  = __shfl_xor(am, x, 64);
        float pdm  = __shfl_xor(dm, x, 64);
        float pTr  = __shfl_xor(Tr, x, 64);
        cm0 = fmaf(Tr, pcm0, cm0);
        cm1 = fmaf(Tr, pcm1, cm1);
        cm2 = fmaf(Tr, pcm2, cm2);
        am  = fmaf(Tr, pam,  am);
        dm  = fmaf(Tr, pdm,  dm);
        Tr *= pTr;
    }

    if (grp == 0) {
        float* o5 = out + (size_t)ray * 5;
        o5[0] = active ? cm0 : 0.0f;
        o5[1] = active ? cm1 : 0.0f;
        o5[2] = active ? cm2 : 0.0f;
        o5[3] = active ? am  : 0.0f;
        o5[4] = active ? dm  : 0.0f;
    }
}

extern "C" void kernel_launch(void* const* d_in, const int* in_sizes, int n_in,
                              void* d_out, int out_size, void* d_ws, size_t ws_size,
                              hipStream_t stream) {
    const float* rays_o = (const float*)d_in[0];
    const float* rays_d = (const float*)d_in[1];
    const float* u      = (const float*)d_in[2];
    const float* aabb   = (const float*)d_in[3];
    const float* W1     = (const float*)d_in[4];
    const float* b1     = (const float*)d_in[5];
    const float* Wsigma = (const float*)d_in[6];
    const float* Wcolor = (const float*)d_in[7];
    const float* Wdir   = (const float*)d_in[8];
    float* out = (float*)d_out;

    int N = in_sizes[0] / 3;
    long long threads = (long long)N * 4;   // 4 lanes (segments) per ray
    int blocks = (int)((threads + 255) / 256);
    radiance_kernel<<<blocks, 256, 0, stream>>>(rays_o, rays_d, u, aabb,
                                                W1, b1, Wsigma, Wcolor, Wdir,
                                                out, N);
}